// Round 3
// baseline (105.425 us; speedup 1.0000x reference)
//
#include <hip/hip_runtime.h>
#include <math.h>

#define EPSF 1e-12f

constexpr int LLEN = 1024;
constexpr int WMAX = 60;
constexpr int LP   = LLEN - WMAX;   // 964
constexpr int NF   = 158;
constexpr int CHUNK = 128;
constexpr int SPAN  = CHUNK + WMAX; // 188
constexpr int NCH   = (LP + CHUNK - 1) / CHUNK; // 8

__device__ __forceinline__ float frcp(float x) {
#if __has_builtin(__builtin_amdgcn_rcpf)
  return __builtin_amdgcn_rcpf(x);
#else
  return 1.0f / x;
#endif
}

// Fully-unrolled bitonic sort on a compile-time-size register array.
template<int N>
__device__ __forceinline__ void bitonic_sort(float (&a)[N]) {
#pragma unroll
  for (int k = 2; k <= N; k <<= 1) {
#pragma unroll
    for (int j = k >> 1; j > 0; j >>= 1) {
#pragma unroll
      for (int i = 0; i < N; ++i) {
        int l = i ^ j;
        if (l > i) {
          float x = a[i], y = a[l];
          float mn = fminf(x, y), mx = fmaxf(x, y);
          if ((i & k) == 0) { a[i] = mn; a[l] = mx; }
          else              { a[i] = mx; a[l] = mn; }
        }
      }
    }
  }
}

// Emit all 29 features of window W_. Uses scan accumulators in scope:
// sc,sc2,sic,sv,sv2,slg,slg2,sclg,cntle,hmax,imax,lmin,imin (pass1, elems i=0..W_-1)
// sr,sr2,sl,sl2,srl,sw,sw2,sp,sn,npos,nneg,dvp,dvn (pass2, pairs i2=0..W_-1)
// c = cs[T-W_] (roc source), cl, rcl, rvA, op.
#define EMITW(W_, FI_, TA_) do {                                              \
  constexpr float wf_  = (float)(W_);                                         \
  constexpr float inw_ = 1.0f / wf_;                                          \
  constexpr float tm_  = (W_ - 1) * 0.5f;                                     \
  constexpr float tv_  = (float)(((double)(W_) * (W_) - 1.0) / 12.0);         \
  constexpr int   k8_  = (int)(0.8 * (W_ - 1));                               \
  constexpr float f8_  = (float)(0.8 * (W_ - 1) - k8_);                       \
  constexpr int   k2_  = (int)(0.2 * (W_ - 1));                               \
  constexpr float f2_  = (float)(0.2 * (W_ - 1) - k2_);                       \
  float qtlu_ = TA_[k8_] + f8_ * (TA_[k8_ + 1] - TA_[k8_]);                   \
  float qtld_ = TA_[k2_] + f2_ * (TA_[k2_ + 1] - TA_[k2_]);                   \
  float scm_  = sc * inw_;                                                    \
  float ym_   = cl + scm_;                                                    \
  float yvar_ = fmaxf(sc2 * inw_ - scm_ * scm_, 0.f);                         \
  float stdv_ = sqrtf(yvar_);                                                 \
  float skc_  = (wf_ - 1.f) * sc - sic;                                       \
  float cov_  = skc_ * inw_ - tm_ * scm_;                                     \
  float slope_ = cov_ * (1.0f / tv_);                                         \
  float rsqr_  = cov_ * cov_ * frcp(tv_ * yvar_ + EPSF);                      \
  float resi_  = (cl - ym_) - slope_ * tm_;                                   \
  float cnum_ = sclg - sc * slg * inw_;                                       \
  float cden_ = sqrtf(fmaxf(sc2 - sc * sc * inw_, 0.f) *                      \
                      fmaxf(slg2 - slg * slg * inw_, 0.f)) + EPSF;            \
  float corr_ = cnum_ * frcp(cden_);                                          \
  float dnum_ = srl - sr * sl * inw_;                                         \
  float dden_ = sqrtf(fmaxf(sr2 - sr * sr * inw_, 0.f) *                      \
                      fmaxf(sl2 - sl * sl * inw_, 0.f)) + EPSF;               \
  float cord_ = dnum_ * frcp(dden_);                                          \
  float absd_ = sp + sn;    float ra_ = frcp(absd_ + EPSF);                   \
  float sump_ = sp * ra_,  sumn_ = sn * ra_;                                  \
  float absv_ = dvp + dvn;  float rv_ = frcp(absv_ + EPSF);                   \
  float vsump_ = dvp * rv_, vsumn_ = dvn * rv_;                               \
  float vmean_ = sv * inw_;                                                   \
  float vvar_  = fmaxf(sv2 * inw_ - vmean_ * vmean_, 0.f);                    \
  float wmean_ = sw * inw_;                                                   \
  float wvar_  = fmaxf(sw2 * inw_ - wmean_ * wmean_, 0.f);                    \
  float cntp_ = (float)npos * inw_, cntn_ = (float)nneg * inw_;               \
  float imaxf_ = (float)((W_ - 1) - imax) * inw_;                             \
  float iminf_ = (float)((W_ - 1) - imin) * inw_;                             \
  op[FI_ + 0]  = c * rcl;                                                     \
  op[FI_ + 1]  = ym_ * rcl;                                                   \
  op[FI_ + 2]  = stdv_ * rcl;                                                 \
  op[FI_ + 3]  = slope_ * rcl;                                                \
  op[FI_ + 4]  = rsqr_;                                                       \
  op[FI_ + 5]  = resi_ * rcl;                                                 \
  op[FI_ + 6]  = hmax * rcl;                                                  \
  op[FI_ + 7]  = lmin * rcl;                                                  \
  op[FI_ + 8]  = qtlu_ * rcl;                                                 \
  op[FI_ + 9]  = qtld_ * rcl;                                                 \
  op[FI_ + 10] = (float)cntle * inw_;                                         \
  op[FI_ + 11] = (cl - lmin) * frcp(hmax - lmin + EPSF);                      \
  op[FI_ + 12] = imaxf_;                                                      \
  op[FI_ + 13] = iminf_;                                                      \
  op[FI_ + 14] = imaxf_ - iminf_;                                             \
  op[FI_ + 15] = corr_;                                                       \
  op[FI_ + 16] = cord_;                                                       \
  op[FI_ + 17] = cntp_;                                                       \
  op[FI_ + 18] = cntn_;                                                       \
  op[FI_ + 19] = cntp_ - cntn_;                                               \
  op[FI_ + 20] = sump_;                                                       \
  op[FI_ + 21] = sumn_;                                                       \
  op[FI_ + 22] = sump_ - sumn_;                                               \
  op[FI_ + 23] = vmean_ * rvA;                                                \
  op[FI_ + 24] = sqrtf(vvar_) * rvA;                                          \
  op[FI_ + 25] = sqrtf(wvar_) * frcp(wmean_ + EPSF);                          \
  op[FI_ + 26] = vsump_;                                                      \
  op[FI_ + 27] = vsumn_;                                                      \
  op[FI_ + 28] = vsump_ - vsumn_;                                             \
} while (0)

__global__ __launch_bounds__(128)
void factor_kernel(const float* __restrict__ x, float* __restrict__ out, int B)
{
  __shared__ float cs[SPAN], hs[SPAN], ls[SPAN], vs[SPAN], lgs[SPAN], lcs[SPAN];

  const int b    = blockIdx.x / NCH;
  const int ch   = blockIdx.x % NCH;
  const int t0   = WMAX + ch * CHUNK;              // first global t of chunk
  const int clen = min(CHUNK, LP - ch * CHUNK);
  const int base = t0 - WMAX;                      // global index of local 0
  const int span = clen + WMAX;
  const int tid  = threadIdx.x;

  // stage raw series
  for (int u = tid; u < span; u += 128) {
    const float* p = x + (size_t)(b * LLEN + base + u) * 6;
    float hv = p[1], lv = p[2], cv = p[3], vv = p[4];
    cs[u] = cv; hs[u] = hv; ls[u] = lv; vs[u] = vv;
    lgs[u] = logf(vv + 1.f);
  }
  __syncthreads();
  // lvchg series (pair (u, u+1)); needs staged vs
  for (int u = tid; u < span - 1; u += 128) {
    lcs[u] = logf(vs[u + 1] / (vs[u] + EPSF) + 1.f);
  }
  __syncthreads();

  if (tid < clen) {
    const int T  = WMAX + tid;     // local index of t
    const int tg = t0 + tid;       // global t

    const float* cb  = cs  + tid;  // cb[WMAX - i] == series[T - i]
    const float* hb  = hs  + tid;
    const float* lb  = ls  + tid;
    const float* vb  = vs  + tid;
    const float* gb  = lgs + tid;
    const float* lcb = lcs + tid;

    const float cl  = cb[WMAX];
    const float vol = vb[WMAX];
    const float lgT = gb[WMAX];
    const float rcl = 1.0f / cl;
    const float rvA = 1.0f / (vol + EPSF);

    float* op = out + ((size_t)b * LP + (tg - WMAX)) * NF;

    // ---- base features ----
    {
      const float* p = x + (size_t)(b * LLEN + tg) * 6;
      float opn = p[0], vwp = p[5];
      float hi = hb[WMAX], lo = lb[WMAX];
      float hl = hi - lo + EPSF;
      float rhl = frcp(hl);
      float ro  = 1.0f / opn;
      float mx_oc = fmaxf(opn, cl), mn_oc = fminf(opn, cl);
      float body2 = 2.f * cl - hi - lo;
      op[0]  = (cl - opn) * ro;
      op[1]  = (hi - lo) * ro;
      op[2]  = (cl - opn) * rhl;
      op[3]  = (hi - mx_oc) * ro;
      op[4]  = (hi - mx_oc) * rhl;
      op[5]  = (mn_oc - lo) * ro;
      op[6]  = (mn_oc - lo) * rhl;
      op[7]  = body2 * ro;
      op[8]  = body2 * rhl;
      op[9]  = opn * rcl;
      op[10] = hi * rcl;
      op[11] = lo * rcl;
      op[12] = vwp * rcl;
    }

    // ---- fused backward scan over i = 0..59 (element j = T-i), emit at i==w ----
    float sarr[64];
    sarr[60] = sarr[61] = sarr[62] = sarr[63] = INFINITY;

    float sc = 0.f, sc2 = 0.f, sic = 0.f;
    float sv = 0.f, sv2 = 0.f;
    float slg = 0.f, slg2 = 0.f, sclg = 0.f;
    int   cntle = 0;
    float hmax = -INFINITY, lmin = INFINITY;
    int   imax = 0, imin = 0;
    float sr = 0.f, sr2 = 0.f, sl = 0.f, sl2 = 0.f, srl = 0.f;
    float sw = 0.f, sw2 = 0.f;
    float sp = 0.f, sn = 0.f, dvp = 0.f, dvn = 0.f;
    int   npos = 0, nneg = 0;
    float pv_c = 0.f, pv_v = 0.f;

#pragma unroll
    for (int i = 0; i < WMAX; ++i) {
      const int q_ = WMAX - i;
      float c = cb[q_], h = hb[q_], l = lb[q_], v = vb[q_], lg = gb[q_];

      // pass2 pair (T-i, T-i+1), valid for i >= 1
      if (i >= 1) {
        float lcv = lcb[q_];
        float d   = pv_c - c;
        float dv  = pv_v - v;
        float r   = pv_c * frcp(c) - 1.f;
        float wvv = fabsf(r) * pv_v;
        sr += r;   sr2 = fmaf(r, r, sr2);
        sl += lcv; sl2 = fmaf(lcv, lcv, sl2); srl = fmaf(r, lcv, srl);
        sw += wvv; sw2 = fmaf(wvv, wvv, sw2);
        npos += (d > 0.f) ? 1 : 0;
        nneg += (d < 0.f) ? 1 : 0;
        sp  += fmaxf(d, 0.f);  sn  += fmaxf(-d, 0.f);
        dvp += fmaxf(dv, 0.f); dvn += fmaxf(-dv, 0.f);
      }

      // window emits (pass1 sums complete through i-1, pass2 pairs through i-1)
      if (i == 5) {
        float t[8];
#pragma unroll
        for (int q = 0; q < 8; ++q) t[q] = (q < 5) ? sarr[q] : INFINITY;
        bitonic_sort<8>(t);
        EMITW(5, 13, t);
      }
      if (i == 10) {
        float t[16];
#pragma unroll
        for (int q = 0; q < 16; ++q) t[q] = (q < 10) ? sarr[q] : INFINITY;
        bitonic_sort<16>(t);
        EMITW(10, 42, t);
      }
      if (i == 20) {
        float t[32];
#pragma unroll
        for (int q = 0; q < 32; ++q) t[q] = (q < 20) ? sarr[q] : INFINITY;
        bitonic_sort<32>(t);
        EMITW(20, 71, t);
      }
      if (i == 30) {
        float t[32];
#pragma unroll
        for (int q = 0; q < 32; ++q) t[q] = (q < 30) ? sarr[q] : INFINITY;
        bitonic_sort<32>(t);
        EMITW(30, 100, t);
      }

      // pass1 element i (j = T-i)
      {
        float cd = c - cl;
        sc += cd; sc2 = fmaf(cd, cd, sc2); sic = fmaf((float)i, cd, sic);
        cntle += (c <= cl) ? 1 : 0;
        if (h >= hmax) { hmax = h; imax = i; }
        if (l <= lmin) { lmin = l; imin = i; }
        sv += v; sv2 = fmaf(v, v, sv2);
        float ld = lg - lgT;
        slg += ld; slg2 = fmaf(ld, ld, slg2); sclg = fmaf(cd, ld, sclg);
        sarr[i] = c;
      }
      pv_c = c; pv_v = v;
    }

    // ---- epilogue: i = 60 (element j = T-60; pass2 pair i2 = 59; emit w=60) ----
    {
      float c = cb[0], v = vb[0];
      float lcv = lcb[0];
      float d   = pv_c - c;
      float dv  = pv_v - v;
      float r   = pv_c * frcp(c) - 1.f;
      float wvv = fabsf(r) * pv_v;
      sr += r;   sr2 = fmaf(r, r, sr2);
      sl += lcv; sl2 = fmaf(lcv, lcv, sl2); srl = fmaf(r, lcv, srl);
      sw += wvv; sw2 = fmaf(wvv, wvv, sw2);
      npos += (d > 0.f) ? 1 : 0;
      nneg += (d < 0.f) ? 1 : 0;
      sp  += fmaxf(d, 0.f);  sn  += fmaxf(-d, 0.f);
      dvp += fmaxf(dv, 0.f); dvn += fmaxf(-dv, 0.f);

      bitonic_sort<64>(sarr);   // in place; sarr dead afterwards
      EMITW(60, 129, sarr);
    }
  }
}

extern "C" void kernel_launch(void* const* d_in, const int* in_sizes, int n_in,
                              void* d_out, int out_size, void* d_ws, size_t ws_size,
                              hipStream_t stream) {
  const float* x = (const float*)d_in[0];
  float* out = (float*)d_out;
  int B = in_sizes[0] / (LLEN * 6);   // 128
  dim3 grid(B * NCH), block(128);
  hipLaunchKernelGGL(factor_kernel, grid, block, 0, stream, x, out, B);
}

// Round 4
// 45.378 us; speedup vs baseline: 2.3233x; 2.3233x over previous
//
#include <hip/hip_runtime.h>
#include <math.h>
#include <utility>

#define EPSF 1e-12f

constexpr int LLEN = 1024;
constexpr int WMAX = 60;
constexpr int LP   = LLEN - WMAX;   // 964
constexpr int NF   = 158;
constexpr int CHUNK = 128;
constexpr int SPAN  = CHUNK + WMAX; // 188
constexpr int NCH   = (LP + CHUNK - 1) / CHUNK; // 8

__device__ __forceinline__ float frcp(float x) {
#if __has_builtin(__builtin_amdgcn_rcpf)
  return __builtin_amdgcn_rcpf(x);
#else
  return 1.0f / x;
#endif
}

// Compile-time unrolled for: calls f(integral_constant<int, I0..I0+N-1>)
template<int I0, class F, int... Is>
__device__ __forceinline__ void unroll_impl(F&& f, std::integer_sequence<int, Is...>) {
  (f(std::integral_constant<int, I0 + Is>{}), ...);
}
template<int I0, int N, class F>
__device__ __forceinline__ void unroll_for(F&& f) {
  unroll_impl<I0>(f, std::make_integer_sequence<int, N>{});
}

// Fully-unrolled bitonic sort on a compile-time-size register array.
template<int N>
__device__ __forceinline__ void bitonic_sort(float (&a)[N]) {
#pragma unroll
  for (int k = 2; k <= N; k <<= 1) {
#pragma unroll
    for (int j = k >> 1; j > 0; j >>= 1) {
#pragma unroll
      for (int i = 0; i < N; ++i) {
        int l = i ^ j;
        if (l > i) {
          float x = a[i], y = a[l];
          float mn = fminf(x, y), mx = fmaxf(x, y);
          if ((i & k) == 0) { a[i] = mn; a[l] = mx; }
          else              { a[i] = mx; a[l] = mn; }
        }
      }
    }
  }
}

// Emit all 29 features of window W_. Scan accumulators in scope; c_ is close[T-W_].
#define EMITW(W_, FI_, TA_) do {                                              \
  constexpr float wf_  = (float)(W_);                                         \
  constexpr float inw_ = 1.0f / wf_;                                          \
  constexpr float tm_  = (W_ - 1) * 0.5f;                                     \
  constexpr float tv_  = (float)(((double)(W_) * (W_) - 1.0) / 12.0);         \
  constexpr int   k8_  = (int)(0.8 * (W_ - 1));                               \
  constexpr float f8_  = (float)(0.8 * (W_ - 1) - k8_);                       \
  constexpr int   k2_  = (int)(0.2 * (W_ - 1));                               \
  constexpr float f2_  = (float)(0.2 * (W_ - 1) - k2_);                       \
  float qtlu_ = TA_[k8_] + f8_ * (TA_[k8_ + 1] - TA_[k8_]);                   \
  float qtld_ = TA_[k2_] + f2_ * (TA_[k2_ + 1] - TA_[k2_]);                   \
  float scm_  = sc * inw_;                                                    \
  float ym_   = cl + scm_;                                                    \
  float yvar_ = fmaxf(sc2 * inw_ - scm_ * scm_, 0.f);                         \
  float stdv_ = sqrtf(yvar_);                                                 \
  float skc_  = (wf_ - 1.f) * sc - sic;                                       \
  float cov_  = skc_ * inw_ - tm_ * scm_;                                     \
  float slope_ = cov_ * (1.0f / tv_);                                         \
  float rsqr_  = cov_ * cov_ * frcp(tv_ * yvar_ + EPSF);                      \
  float resi_  = (cl - ym_) - slope_ * tm_;                                   \
  float cnum_ = sclg - sc * slg * inw_;                                       \
  float cden_ = sqrtf(fmaxf(sc2 - sc * sc * inw_, 0.f) *                      \
                      fmaxf(slg2 - slg * slg * inw_, 0.f)) + EPSF;            \
  float corr_ = cnum_ * frcp(cden_);                                          \
  float dnum_ = srl - sr * sl * inw_;                                         \
  float dden_ = sqrtf(fmaxf(sr2 - sr * sr * inw_, 0.f) *                      \
                      fmaxf(sl2 - sl * sl * inw_, 0.f)) + EPSF;               \
  float cord_ = dnum_ * frcp(dden_);                                          \
  float absd_ = sp + sn;    float ra_ = frcp(absd_ + EPSF);                   \
  float sump_ = sp * ra_,  sumn_ = sn * ra_;                                  \
  float absv_ = dvp + dvn;  float rv_ = frcp(absv_ + EPSF);                   \
  float vsump_ = dvp * rv_, vsumn_ = dvn * rv_;                               \
  float vmean_ = sv * inw_;                                                   \
  float vvar_  = fmaxf(sv2 * inw_ - vmean_ * vmean_, 0.f);                    \
  float wmean_ = sw * inw_;                                                   \
  float wvar_  = fmaxf(sw2 * inw_ - wmean_ * wmean_, 0.f);                    \
  float cntp_ = (float)npos * inw_, cntn_ = (float)nneg * inw_;               \
  float imaxf_ = (float)((W_ - 1) - imax) * inw_;                             \
  float iminf_ = (float)((W_ - 1) - imin) * inw_;                             \
  op[FI_ + 0]  = c_ * rcl;                                                    \
  op[FI_ + 1]  = ym_ * rcl;                                                   \
  op[FI_ + 2]  = stdv_ * rcl;                                                 \
  op[FI_ + 3]  = slope_ * rcl;                                                \
  op[FI_ + 4]  = rsqr_;                                                       \
  op[FI_ + 5]  = resi_ * rcl;                                                 \
  op[FI_ + 6]  = hmax * rcl;                                                  \
  op[FI_ + 7]  = lmin * rcl;                                                  \
  op[FI_ + 8]  = qtlu_ * rcl;                                                 \
  op[FI_ + 9]  = qtld_ * rcl;                                                 \
  op[FI_ + 10] = (float)cntle * inw_;                                         \
  op[FI_ + 11] = (cl - lmin) * frcp(hmax - lmin + EPSF);                      \
  op[FI_ + 12] = imaxf_;                                                      \
  op[FI_ + 13] = iminf_;                                                      \
  op[FI_ + 14] = imaxf_ - iminf_;                                             \
  op[FI_ + 15] = corr_;                                                       \
  op[FI_ + 16] = cord_;                                                       \
  op[FI_ + 17] = cntp_;                                                       \
  op[FI_ + 18] = cntn_;                                                       \
  op[FI_ + 19] = cntp_ - cntn_;                                               \
  op[FI_ + 20] = sump_;                                                       \
  op[FI_ + 21] = sumn_;                                                       \
  op[FI_ + 22] = sump_ - sumn_;                                               \
  op[FI_ + 23] = vmean_ * rvA;                                                \
  op[FI_ + 24] = sqrtf(vvar_) * rvA;                                          \
  op[FI_ + 25] = sqrtf(wvar_) * frcp(wmean_ + EPSF);                          \
  op[FI_ + 26] = vsump_;                                                      \
  op[FI_ + 27] = vsumn_;                                                      \
  op[FI_ + 28] = vsump_ - vsumn_;                                             \
} while (0)

__global__ __launch_bounds__(128, 2)
void factor_kernel(const float* __restrict__ x, float* __restrict__ out, int B)
{
  __shared__ float cs[SPAN], hs[SPAN], ls[SPAN], vs[SPAN], lgs[SPAN];

  const int b    = blockIdx.x / NCH;
  const int ch   = blockIdx.x % NCH;
  const int t0   = WMAX + ch * CHUNK;              // first global t of chunk
  const int clen = min(CHUNK, LP - ch * CHUNK);
  const int base = t0 - WMAX;                      // global index of local 0
  const int span = clen + WMAX;
  const int tid  = threadIdx.x;

  // stage raw series
  for (int u = tid; u < span; u += 128) {
    const float* p = x + (size_t)(b * LLEN + base + u) * 6;
    float hv = p[1], lv = p[2], cv = p[3], vv = p[4];
    cs[u] = cv; hs[u] = hv; ls[u] = lv; vs[u] = vv;
    lgs[u] = logf(vv + 1.f);
  }
  __syncthreads();

  if (tid < clen) {
    const int tg = t0 + tid;       // global t

    const float* cb = cs  + tid;   // cb[WMAX - i] == series[T - i]
    const float* hb = hs  + tid;
    const float* lb = ls  + tid;
    const float* vb = vs  + tid;
    const float* gb = lgs + tid;

    const float cl  = cb[WMAX];
    const float vol = vb[WMAX];
    const float lgT = gb[WMAX];
    const float rcl = 1.0f / cl;
    const float rvA = 1.0f / (vol + EPSF);

    float* op = out + ((size_t)b * LP + (tg - WMAX)) * NF;

    // ---- base features ----
    {
      const float* p = x + (size_t)(b * LLEN + tg) * 6;
      float opn = p[0], vwp = p[5];
      float hi = hb[WMAX], lo = lb[WMAX];
      float hl = hi - lo + EPSF;
      float rhl = frcp(hl);
      float ro  = 1.0f / opn;
      float mx_oc = fmaxf(opn, cl), mn_oc = fminf(opn, cl);
      float body2 = 2.f * cl - hi - lo;
      op[0]  = (cl - opn) * ro;
      op[1]  = (hi - lo) * ro;
      op[2]  = (cl - opn) * rhl;
      op[3]  = (hi - mx_oc) * ro;
      op[4]  = (hi - mx_oc) * rhl;
      op[5]  = (mn_oc - lo) * ro;
      op[6]  = (mn_oc - lo) * rhl;
      op[7]  = body2 * ro;
      op[8]  = body2 * rhl;
      op[9]  = opn * rcl;
      op[10] = hi * rcl;
      op[11] = lo * rcl;
      op[12] = vwp * rcl;
    }

    // ---- fused backward scan, compile-time segmented ----
    float sarr[64];
    sarr[60] = sarr[61] = sarr[62] = sarr[63] = INFINITY;

    float sc = 0.f, sc2 = 0.f, sic = 0.f;
    float sv = 0.f, sv2 = 0.f;
    float slg = 0.f, slg2 = 0.f, sclg = 0.f;
    int   cntle = 0;
    float hmax = -INFINITY, lmin = INFINITY;
    int   imax = 0, imin = 0;
    float sr = 0.f, sr2 = 0.f, sl = 0.f, sl2 = 0.f, srl = 0.f;
    float sw = 0.f, sw2 = 0.f;
    float sp = 0.f, sn = 0.f, dvp = 0.f, dvn = 0.f;
    int   npos = 0, nneg = 0;
    float pv_c = 0.f, pv_v = 0.f;
    float c_ = 0.f, h_ = 0.f, l_ = 0.f, v_ = 0.f, lg_ = 0.f;

    // load element i (= series index T-i) + pass2 pair (T-i, T-i+1) for i>=1
    auto load2 = [&](auto ic) {
      constexpr int i = decltype(ic)::value;
      constexpr int q = WMAX - i;
      c_ = cb[q]; v_ = vb[q];
      if constexpr (i < WMAX) { h_ = hb[q]; l_ = lb[q]; lg_ = gb[q]; }
      if constexpr (i >= 1) {
        float d   = pv_c - c_;
        float dv  = pv_v - v_;
        float r   = pv_c * frcp(c_) - 1.f;
        float lcv = __logf(pv_v * frcp(v_ + EPSF) + 1.f);
        float wvv = fabsf(r) * pv_v;
        sr += r;   sr2 = fmaf(r, r, sr2);
        sl += lcv; sl2 = fmaf(lcv, lcv, sl2); srl = fmaf(r, lcv, srl);
        sw += wvv; sw2 = fmaf(wvv, wvv, sw2);
        npos += (d > 0.f) ? 1 : 0;
        nneg += (d < 0.f) ? 1 : 0;
        sp  += fmaxf(d, 0.f);  sn  += fmaxf(-d, 0.f);
        dvp += fmaxf(dv, 0.f); dvn += fmaxf(-dv, 0.f);
      }
    };
    // pass1 for element i
    auto p1 = [&](auto ic) {
      constexpr int i = decltype(ic)::value;
      float cd = c_ - cl;
      sc += cd; sc2 = fmaf(cd, cd, sc2); sic = fmaf((float)i, cd, sic);
      cntle += (c_ <= cl) ? 1 : 0;
      if (h_ >= hmax) { hmax = h_; imax = i; }
      if (l_ <= lmin) { lmin = l_; imin = i; }
      sv += v_; sv2 = fmaf(v_, v_, sv2);
      float ld = lg_ - lgT;
      slg += ld; slg2 = fmaf(ld, ld, slg2); sclg = fmaf(cd, ld, sclg);
      sarr[i] = c_;
      pv_c = c_; pv_v = v_;
    };
    auto step = [&](auto ic) { load2(ic); p1(ic); };

    unroll_for<0, 5>(step);                       // i = 0..4
    load2(std::integral_constant<int, 5>{});
    {
      float t[8];
      unroll_for<0, 8>([&](auto q) {
        constexpr int qq = decltype(q)::value;
        t[qq] = (qq < 5) ? sarr[qq] : INFINITY;
      });
      bitonic_sort<8>(t);
      EMITW(5, 13, t);
    }
    p1(std::integral_constant<int, 5>{});

    unroll_for<6, 4>(step);                       // i = 6..9
    load2(std::integral_constant<int, 10>{});
    {
      float t[16];
      unroll_for<0, 16>([&](auto q) {
        constexpr int qq = decltype(q)::value;
        t[qq] = (qq < 10) ? sarr[qq] : INFINITY;
      });
      bitonic_sort<16>(t);
      EMITW(10, 42, t);
    }
    p1(std::integral_constant<int, 10>{});

    unroll_for<11, 9>(step);                      // i = 11..19
    load2(std::integral_constant<int, 20>{});
    {
      float t[32];
      unroll_for<0, 32>([&](auto q) {
        constexpr int qq = decltype(q)::value;
        t[qq] = (qq < 20) ? sarr[qq] : INFINITY;
      });
      bitonic_sort<32>(t);
      EMITW(20, 71, t);
    }
    p1(std::integral_constant<int, 20>{});

    unroll_for<21, 9>(step);                      // i = 21..29
    load2(std::integral_constant<int, 30>{});
    {
      float t[32];
      unroll_for<0, 32>([&](auto q) {
        constexpr int qq = decltype(q)::value;
        t[qq] = (qq < 30) ? sarr[qq] : INFINITY;
      });
      bitonic_sort<32>(t);
      EMITW(30, 100, t);
    }
    p1(std::integral_constant<int, 30>{});

    unroll_for<31, 29>(step);                     // i = 31..59

    // i = 60: pass2 pair (T-60, T-59), sort all 60, emit w=60
    load2(std::integral_constant<int, 60>{});
    bitonic_sort<64>(sarr);
    EMITW(60, 129, sarr);
  }
}

extern "C" void kernel_launch(void* const* d_in, const int* in_sizes, int n_in,
                              void* d_out, int out_size, void* d_ws, size_t ws_size,
                              hipStream_t stream) {
  const float* x = (const float*)d_in[0];
  float* out = (float*)d_out;
  int B = in_sizes[0] / (LLEN * 6);   // 128
  dim3 grid(B * NCH), block(128);
  hipLaunchKernelGGL(factor_kernel, grid, block, 0, stream, x, out, B);
}